// Round 8
// baseline (2040.320 us; speedup 1.0000x reference)
//
#include <hip/hip_runtime.h>

// Problem constants.
#define KK 27
#define PP 100000
#define RTOT (KK * PP)        // 2,700,000 pairs
#define C_IN 32
#define C_OUT 32
#define N_IN 200000
#define N_OUT 400000

// Scan geometry: 1024 counters per block, 391 blocks.
#define SCAN_CHUNK 1024
#define NB_SCAN ((N_OUT + SCAN_CHUNK - 1) / SCAN_CHUNK)   // 391

typedef float vfloat4 __attribute__((ext_vector_type(4)));

// ---------------------------------------------------------------------------
// ws layout (uint32 units):
//   cnt    [400000]   histogram, then reused as scatter cursor (ends = off+len)
//   off    [400000]   exclusive row offsets (stable)
//   bsum   [512]      scan block sums
//   WT     [27648]    transposed weights [k][co][ci] (110.6 KB)
//   bucket [2700000]  packed (k<<18 | pin) per pair, grouped by output row
// total ~14.1 MB
// ---------------------------------------------------------------------------

// 1) zero the histogram (ws is poisoned 0xAA before every launch)
__global__ __launch_bounds__(256) void zero_cnt_kernel(unsigned* __restrict__ cnt) {
    int i = blockIdx.x * 256 + threadIdx.x;
    if (i < N_OUT) cnt[i] = 0u;
}

// 2) histogram: count pairs per output row (int atomics on 1.6MB array)
__global__ __launch_bounds__(256) void hist_kernel(
    const int* __restrict__ pout, unsigned* __restrict__ cnt) {
    int g = blockIdx.x * 256 + threadIdx.x;
    if (g < RTOT) atomicAdd(&cnt[pout[g]], 1u);
}

// 3) scan, stage 1: per-1024-chunk exclusive scan + block sums
__global__ __launch_bounds__(256) void scan1_kernel(
    const unsigned* __restrict__ cnt, unsigned* __restrict__ off,
    unsigned* __restrict__ bsum) {
    __shared__ unsigned ts[256];
    const int b = blockIdx.x, t = threadIdx.x;
    const int base = b * SCAN_CHUNK + t * 4;
    unsigned v[4], s = 0;
#pragma unroll
    for (int j = 0; j < 4; ++j) {
        v[j] = (base + j < N_OUT) ? cnt[base + j] : 0u;
        s += v[j];
    }
    ts[t] = s;
    __syncthreads();
    for (int o = 1; o < 256; o <<= 1) {
        unsigned x = (t >= o) ? ts[t - o] : 0u;
        __syncthreads();
        ts[t] += x;
        __syncthreads();
    }
    unsigned excl = ts[t] - s;
    if (t == 255) bsum[b] = ts[255];
    unsigned run = excl;
#pragma unroll
    for (int j = 0; j < 4; ++j) {
        if (base + j < N_OUT) off[base + j] = run;
        run += v[j];
    }
}

// 4) scan, stage 2: exclusive scan of the 391 block sums (single block)
__global__ __launch_bounds__(512) void scan2_kernel(unsigned* __restrict__ bsum) {
    __shared__ unsigned ts[512];
    const int t = threadIdx.x;
    unsigned s = (t < NB_SCAN) ? bsum[t] : 0u;
    ts[t] = s;
    __syncthreads();
    for (int o = 1; o < 512; o <<= 1) {
        unsigned x = (t >= o) ? ts[t - o] : 0u;
        __syncthreads();
        ts[t] += x;
        __syncthreads();
    }
    if (t < NB_SCAN) bsum[t] = ts[t] - s;   // exclusive
}

// 5) scan, stage 3: add block base; init cursor (cnt := off)
__global__ __launch_bounds__(256) void scan3_kernel(
    unsigned* __restrict__ off, unsigned* __restrict__ cnt,
    const unsigned* __restrict__ bsum) {
    const int b = blockIdx.x, t = threadIdx.x;
    const int base = b * SCAN_CHUNK + t * 4;
    const unsigned add = bsum[b];
#pragma unroll
    for (int j = 0; j < 4; ++j) {
        if (base + j < N_OUT) {
            unsigned o = off[base + j] + add;
            off[base + j] = o;
            cnt[base + j] = o;              // cursor starts at row offset
        }
    }
}

// 6) scatter pair IDs into row buckets. After this, cnt[r] == off[r] + len[r].
__global__ __launch_bounds__(256) void scatter_kernel(
    const int* __restrict__ pin, const int* __restrict__ pout,
    unsigned* __restrict__ cnt, unsigned* __restrict__ bucket) {
    int g = blockIdx.x * 256 + threadIdx.x;
    if (g < RTOT) {
        const int row = pout[g];
        const int k   = g / PP;             // magic-mul by compiler
        const unsigned pk = ((unsigned)k << 18) | (unsigned)pin[g];
        const unsigned pos = atomicAdd(&cnt[row], 1u);
        bucket[pos] = pk;
    }
}

// 7) transpose weights: WT[k][co][ci] = W[k][ci][co]  (27648 elements)
__global__ __launch_bounds__(256) void wt_kernel(
    const float* __restrict__ weight, float* __restrict__ WT) {
    int i = blockIdx.x * 256 + threadIdx.x;   // grid covers exactly 27648
    const int k  = i / (C_IN * C_OUT);
    const int r  = i % (C_IN * C_OUT);
    const int co = r / C_IN;
    const int ci = r % C_IN;
    WT[i] = weight[k * (C_IN * C_OUT) + ci * C_OUT + co];
}

// 8) gather-reduce: one 32-lane group reduces 4 output rows; lane = channel.
//    Plain stores, bias fused, zero fp32 atomics.
#define ROWS_PER_GROUP 4
#define GATHER_BLOCKS (N_OUT / (8 * ROWS_PER_GROUP))   // 12500
__global__ __launch_bounds__(256) void gather_kernel(
    const float* __restrict__ feats,      // [N_IN, 32]
    const float* __restrict__ WT,         // [K][co][ci]
    const unsigned* __restrict__ off,     // row start
    const unsigned* __restrict__ cnt,     // row end (post-scatter cursor)
    const unsigned* __restrict__ bucket,  // packed (k<<18|ii)
    const float* __restrict__ bias,
    float* __restrict__ out)              // [N_OUT, 32]
{
    const int c   = threadIdx.x & 31;
    const int grp = threadIdx.x >> 5;
    const int gid = blockIdx.x * 8 + grp;
    const float bv = bias[c];

#pragma unroll
    for (int rr = 0; rr < ROWS_PER_GROUP; ++rr) {
        const int r = gid * ROWS_PER_GROUP + rr;
        const unsigned start = off[r];
        const unsigned end   = cnt[r];
        float acc = 0.0f;
        for (unsigned e = start; e < end; ++e) {
            const unsigned pk = bucket[e];
            const int k  = (int)(pk >> 18);
            const int ii = (int)(pk & 0x3FFFFu);
            const vfloat4* f4 = (const vfloat4*)(feats + ii * C_IN);
            const vfloat4* w4 = (const vfloat4*)(WT + k * (C_IN * C_OUT) + c * C_IN);
#pragma unroll
            for (int j = 0; j < 8; ++j) {
                const vfloat4 f = f4[j];   // broadcast across the 32-lane group
                const vfloat4 w = w4[j];   // per-lane contiguous 16B
                acc = fmaf(f.x, w.x, acc);
                acc = fmaf(f.y, w.y, acc);
                acc = fmaf(f.z, w.z, acc);
                acc = fmaf(f.w, w.w, acc);
            }
        }
        out[r * C_OUT + c] = acc + bv;
    }
}

// ---------------------------------------------------------------------------
// Launch
// ---------------------------------------------------------------------------
extern "C" void kernel_launch(void* const* d_in, const int* in_sizes, int n_in,
                              void* d_out, int out_size, void* d_ws, size_t ws_size,
                              hipStream_t stream) {
    const float* feats  = (const float*)d_in[0];       // [N_IN, 32]
    const float* weight = (const float*)d_in[1];       // [K, 32, 32]
    const float* bias   = (const float*)d_in[2];       // [32]
    const int*   pin    = (const int*)d_in[3];         // [K, P] int32
    const int*   pout   = (const int*)d_in[4];         // [K, P] int32
    float*       out    = (float*)d_out;               // [N_OUT, 32]

    unsigned* cnt    = (unsigned*)d_ws;                // 400000
    unsigned* off    = cnt + N_OUT;                    // 400000
    unsigned* bsum   = off + N_OUT;                    // 512
    float*    WT     = (float*)(bsum + 512);           // 27648 (16B-aligned)
    unsigned* bucket = (unsigned*)(WT + KK * C_IN * C_OUT);  // 2,700,000

    const int pair_blocks = (RTOT + 255) / 256;        // 10547

    zero_cnt_kernel<<<(N_OUT + 255) / 256, 256, 0, stream>>>(cnt);
    hist_kernel<<<pair_blocks, 256, 0, stream>>>(pout, cnt);
    scan1_kernel<<<NB_SCAN, 256, 0, stream>>>(cnt, off, bsum);
    scan2_kernel<<<1, 512, 0, stream>>>(bsum);
    scan3_kernel<<<NB_SCAN, 256, 0, stream>>>(off, cnt, bsum);
    scatter_kernel<<<pair_blocks, 256, 0, stream>>>(pin, pout, cnt, bucket);
    wt_kernel<<<(KK * C_IN * C_OUT) / 256, 256, 0, stream>>>(weight, WT);
    gather_kernel<<<GATHER_BLOCKS, 256, 0, stream>>>(
        feats, WT, off, cnt, bucket, bias, out);
}

// Round 9
// 643.139 us; speedup vs baseline: 3.1724x; 3.1724x over previous
//
#include <hip/hip_runtime.h>

// Problem constants.
#define KK 27
#define PP 100000
#define RTOT (KK * PP)          // 2,700,000
#define C_IN 32
#define C_OUT 32
#define N_IN 200000
#define N_OUT 400000

// Coarse-bucket geometry.
#define RPB 128                 // rows per bucket (8 output rows * 16 sweeps)
#define NBUCK (N_OUT / RPB)     // 3125 buckets, 16KB fp32 accum each
#define NBLKA 450               // binning blocks
#define CHA (RTOT / NBLKA)      // 6000 pairs per binning block

typedef float vfloat4 __attribute__((ext_vector_type(4)));

// ---------------------------------------------------------------------------
// ws layout (u32 units):
//   C    [NBLKA*NBUCK = 1,406,250]  per-(block,bucket) counts -> in-place excl scan
//   T    [NBUCK]                    per-bucket totals
//   base [NBUCK+1]                  global bucket offsets
//   bucket [RTOT = 2,700,000]       packed entries (k<<25 | row7<<18 | pin)
// total ~16.5 MB. Everything is fully rewritten every launch (0xAA-safe).
// ---------------------------------------------------------------------------

// A1: per-block coarse histogram -> C[blk][buck]  (LDS atomics only)
__global__ __launch_bounds__(256) void countA_kernel(
    const int* __restrict__ pout, unsigned* __restrict__ C) {
    __shared__ unsigned h[NBUCK];
    const int t = threadIdx.x, blk = blockIdx.x;
    for (int j = t; j < NBUCK; j += 256) h[j] = 0u;
    __syncthreads();
    const int g0 = blk * CHA;
    for (int i = t; i < CHA; i += 256)
        atomicAdd(&h[pout[g0 + i] >> 7], 1u);
    __syncthreads();
    unsigned* Crow = C + (size_t)blk * NBUCK;
    for (int j = t; j < NBUCK; j += 256) Crow[j] = h[j];
}

// S1: column-wise exclusive scan of C in place; totals -> T.
//     thread b owns bucket-column b; all accesses coalesced across threads.
__global__ __launch_bounds__(256) void scanCols_kernel(
    unsigned* __restrict__ C, unsigned* __restrict__ T) {
    const int b = blockIdx.x * 256 + threadIdx.x;
    if (b >= NBUCK) return;
    unsigned run = 0;
    for (int blk = 0; blk < NBLKA; ++blk) {
        const size_t idx = (size_t)blk * NBUCK + b;
        const unsigned v = C[idx];
        C[idx] = run;
        run += v;
    }
    T[b] = run;
}

// S2: single-block exclusive scan of T[3125] -> base[3126].
__global__ __launch_bounds__(1024) void scanBase_kernel(
    const unsigned* __restrict__ T, unsigned* __restrict__ base) {
    __shared__ unsigned ts[1024];
    const int t = threadIdx.x;
    const int i0 = t * 4;
    unsigned v[4], s = 0;
#pragma unroll
    for (int j = 0; j < 4; ++j) {
        v[j] = (i0 + j < NBUCK) ? T[i0 + j] : 0u;
        s += v[j];
    }
    ts[t] = s;
    __syncthreads();
    for (int o = 1; o < 1024; o <<= 1) {
        unsigned x = (t >= o) ? ts[t - o] : 0u;
        __syncthreads();
        ts[t] += x;
        __syncthreads();
    }
    unsigned run = ts[t] - s;   // exclusive base for this thread's 4 elements
#pragma unroll
    for (int j = 0; j < 4; ++j) {
        if (i0 + j < NBUCK) base[i0 + j] = run;
        run += v[j];
    }
    if (t == 0) base[NBUCK] = (unsigned)RTOT;
}

// A2: scatter packed entries into buckets. LDS cursors (no global atomics).
//     Positions are monotone in pair index g => bucket contents k-sorted.
__global__ __launch_bounds__(256) void scatterA_kernel(
    const int* __restrict__ pin, const int* __restrict__ pout,
    const unsigned* __restrict__ C, const unsigned* __restrict__ base,
    unsigned* __restrict__ bucket) {
    __shared__ unsigned curs[NBUCK];
    const int t = threadIdx.x, blk = blockIdx.x;
    const unsigned* Prow = C + (size_t)blk * NBUCK;
    for (int j = t; j < NBUCK; j += 256) curs[j] = base[j] + Prow[j];
    __syncthreads();
    const int g0 = blk * CHA;
    for (int i = t; i < CHA; i += 256) {
        const int g   = g0 + i;
        const int row = pout[g];
        const unsigned k  = (unsigned)g / PP;                  // magic-mul
        const unsigned pk = (k << 25) | ((unsigned)(row & 127) << 18)
                          | (unsigned)pin[g];
        const unsigned pos = atomicAdd(&curs[row >> 7], 1u);   // LDS atomic
        bucket[pos] = pk;
    }
}

// B: per-bucket gather-GEMM-accumulate. One block per bucket (128 rows).
//    lane c = output channel; 8 groups split the (k-sorted) entry list;
//    weights live in registers per k-run; 2 entries in flight for MLP.
__global__ __launch_bounds__(256) void gather_accum_kernel(
    const float* __restrict__ feats,      // [N_IN, 32]
    const float* __restrict__ weight,     // [K, ci, co] (original layout)
    const unsigned* __restrict__ base,    // [NBUCK+1]
    const unsigned* __restrict__ bucket,  // packed entries
    const float* __restrict__ bias,
    float* __restrict__ out)              // [N_OUT, 32]
{
    __shared__ float accum[RPB][C_OUT];   // 16 KB
    const int t = threadIdx.x, b = blockIdx.x;
    const int c = t & 31, grp = t >> 5;

    for (int j = t; j < RPB * C_OUT; j += 256) ((float*)accum)[j] = 0.0f;
    __syncthreads();

    const int s0  = (int)base[b];
    const int len = (int)base[b + 1] - s0;
    int e        = s0 + (len * grp) / 8;
    const int ee = s0 + (len * (grp + 1)) / 8;

    int kc = -1;
    float wcol[C_IN];

    // main loop: 2 entries in flight (16 outstanding feats loads)
    for (; e + 1 < ee; e += 2) {
        const unsigned pk0 = bucket[e];
        const unsigned pk1 = bucket[e + 1];
        const vfloat4* f0p = (const vfloat4*)(feats + (pk0 & 0x3FFFFu) * C_IN);
        const vfloat4* f1p = (const vfloat4*)(feats + (pk1 & 0x3FFFFu) * C_IN);
        vfloat4 f0[8], f1[8];
#pragma unroll
        for (int j = 0; j < 8; ++j) f0[j] = f0p[j];
#pragma unroll
        for (int j = 0; j < 8; ++j) f1[j] = f1p[j];

        const int k0 = (int)(pk0 >> 25);
        if (k0 != kc) {
            kc = k0;
            const float* w = weight + k0 * (C_IN * C_OUT) + c;
#pragma unroll
            for (int ci = 0; ci < C_IN; ++ci) wcol[ci] = w[ci * C_OUT];
        }
        float a0 = 0.0f;
#pragma unroll
        for (int j = 0; j < 8; ++j) {
            a0 = fmaf(f0[j].x, wcol[4 * j + 0], a0);
            a0 = fmaf(f0[j].y, wcol[4 * j + 1], a0);
            a0 = fmaf(f0[j].z, wcol[4 * j + 2], a0);
            a0 = fmaf(f0[j].w, wcol[4 * j + 3], a0);
        }
        atomicAdd(&accum[(pk0 >> 18) & 127][c], a0);

        const int k1 = (int)(pk1 >> 25);
        if (k1 != kc) {
            kc = k1;
            const float* w = weight + k1 * (C_IN * C_OUT) + c;
#pragma unroll
            for (int ci = 0; ci < C_IN; ++ci) wcol[ci] = w[ci * C_OUT];
        }
        float a1 = 0.0f;
#pragma unroll
        for (int j = 0; j < 8; ++j) {
            a1 = fmaf(f1[j].x, wcol[4 * j + 0], a1);
            a1 = fmaf(f1[j].y, wcol[4 * j + 1], a1);
            a1 = fmaf(f1[j].z, wcol[4 * j + 2], a1);
            a1 = fmaf(f1[j].w, wcol[4 * j + 3], a1);
        }
        atomicAdd(&accum[(pk1 >> 18) & 127][c], a1);
    }
    // tail (0 or 1 entry)
    for (; e < ee; ++e) {
        const unsigned pk = bucket[e];
        const vfloat4* fp = (const vfloat4*)(feats + (pk & 0x3FFFFu) * C_IN);
        vfloat4 f[8];
#pragma unroll
        for (int j = 0; j < 8; ++j) f[j] = fp[j];
        const int k = (int)(pk >> 25);
        if (k != kc) {
            kc = k;
            const float* w = weight + k * (C_IN * C_OUT) + c;
#pragma unroll
            for (int ci = 0; ci < C_IN; ++ci) wcol[ci] = w[ci * C_OUT];
        }
        float a = 0.0f;
#pragma unroll
        for (int j = 0; j < 8; ++j) {
            a = fmaf(f[j].x, wcol[4 * j + 0], a);
            a = fmaf(f[j].y, wcol[4 * j + 1], a);
            a = fmaf(f[j].z, wcol[4 * j + 2], a);
            a = fmaf(f[j].w, wcol[4 * j + 3], a);
        }
        atomicAdd(&accum[(pk >> 18) & 127][c], a);
    }

    __syncthreads();
    // write 128 rows, bias fused, fully coalesced (1 KB per sweep)
    const int R0 = b * RPB;
    const float bv = bias[c];
#pragma unroll
    for (int j = 0; j < RPB / 8; ++j) {
        const int r = grp + 8 * j;
        out[(R0 + r) * C_OUT + c] = accum[r][c] + bv;
    }
}

// ---------------------------------------------------------------------------
// Launch
// ---------------------------------------------------------------------------
extern "C" void kernel_launch(void* const* d_in, const int* in_sizes, int n_in,
                              void* d_out, int out_size, void* d_ws, size_t ws_size,
                              hipStream_t stream) {
    const float* feats  = (const float*)d_in[0];       // [N_IN, 32]
    const float* weight = (const float*)d_in[1];       // [K, 32, 32]
    const float* bias   = (const float*)d_in[2];       // [32]
    const int*   pin    = (const int*)d_in[3];         // [K, P] int32
    const int*   pout   = (const int*)d_in[4];         // [K, P] int32
    float*       out    = (float*)d_out;               // [N_OUT, 32]

    unsigned* C      = (unsigned*)d_ws;                       // 1,406,250
    unsigned* T      = C + (size_t)NBLKA * NBUCK;             // 3125
    unsigned* base   = T + NBUCK;                             // 3126
    unsigned* bucket = base + (NBUCK + 1);                    // 2,700,000

    countA_kernel  <<<NBLKA, 256, 0, stream>>>(pout, C);
    scanCols_kernel<<<(NBUCK + 255) / 256, 256, 0, stream>>>(C, T);
    scanBase_kernel<<<1, 1024, 0, stream>>>(T, base);
    scatterA_kernel<<<NBLKA, 256, 0, stream>>>(pin, pout, C, base, bucket);
    gather_accum_kernel<<<NBUCK, 256, 0, stream>>>(
        feats, weight, base, bucket, bias, out);
}